// Round 8
// baseline (414.275 us; speedup 1.0000x reference)
//
#include <hip/hip_runtime.h>
#include <hip/hip_bf16.h>
#include <stdint.h>
#include <type_traits>

// B=16384, IN=1024, H=1024, K = IN+H = 2048
// Gate order: 0=i, 1=f, 2=o, 3=u
// ws: A_bf16 [16384][2048] @ 0 (64 MiB); B_bf16 [4][1024][2048] (j-major = W^T) @ 64 MiB

typedef short bf16x8 __attribute__((ext_vector_type(8)));
typedef unsigned short u16x8 __attribute__((ext_vector_type(8)));
typedef float f32x4 __attribute__((ext_vector_type(4)));

__device__ __forceinline__ unsigned short f2bf(float f) {
    union { float f; uint32_t u; } v; v.f = f;
    uint32_t r = v.u + 0x7FFFu + ((v.u >> 16) & 1u);   // RNE
    return (unsigned short)(r >> 16);
}

__device__ __forceinline__ float fsig(float x) { return 1.0f / (1.0f + __expf(-x)); }
__device__ __forceinline__ float ftanh(float x) { return 2.0f * fsig(2.0f * x) - 1.0f; }

// ---------------- pack A: [input | prev_h] -> bf16 [16384][2048] ----------------
__global__ __launch_bounds__(256) void pack_a_kernel(const float* __restrict__ input,
                                                     const float* __restrict__ prev_h,
                                                     unsigned short* __restrict__ Apk) {
    long idx = (long)blockIdx.x * 256 + threadIdx.x;
    long e0 = idx * 8;
    int b = (int)(e0 >> 11);
    int k = (int)(e0 & 2047);
    const float* src = (k < 1024) ? (input + (size_t)b * 1024 + k)
                                  : (prev_h + (size_t)b * 1024 + (k - 1024));
    float4 lo = *(const float4*)src;
    float4 hi = *(const float4*)(src + 4);
    u16x8 o;
    o[0] = f2bf(lo.x); o[1] = f2bf(lo.y); o[2] = f2bf(lo.z); o[3] = f2bf(lo.w);
    o[4] = f2bf(hi.x); o[5] = f2bf(hi.y); o[6] = f2bf(hi.z); o[7] = f2bf(hi.w);
    *(u16x8*)(Apk + e0) = o;
}

// ---------------- pack B: per-gate W^T (j-major) bf16 [4][1024][2048] ----------------
__global__ __launch_bounds__(256) void pack_b_kernel(
        const float* __restrict__ wxi, const float* __restrict__ wxf,
        const float* __restrict__ wxo, const float* __restrict__ wxu,
        const float* __restrict__ whi, const float* __restrict__ whf,
        const float* __restrict__ who, const float* __restrict__ whu,
        unsigned short* __restrict__ Bpk) {
    int idx = blockIdx.x * 256 + threadIdx.x;
    int g  = idx >> 18;
    int r  = idx & 262143;
    int kc = r >> 10;
    int j  = r & 1023;
    const float* wx = (g == 0) ? wxi : (g == 1) ? wxf : (g == 2) ? wxo : wxu;
    const float* wh = (g == 0) ? whi : (g == 1) ? whf : (g == 2) ? who : whu;
    int k0 = kc * 8;
    const float* src = (k0 < 1024) ? (wx + (size_t)k0 * 1024 + j)
                                   : (wh + (size_t)(k0 - 1024) * 1024 + j);
    u16x8 o;
#pragma unroll
    for (int t = 0; t < 8; ++t) o[t] = f2bf(src[(size_t)t * 1024]);
    *(u16x8*)(Bpk + (((size_t)(g * 1024 + j)) << 11) + k0) = o;
}

// ---------------- fused GEMM + LSTM epilogue ----------------
// grid 1024 = 64 rowTiles x 16 colTiles; block 512 = 8 waves.
// wave w: wm = w>>2 (128-row half), wq = w&3 (16-col quarter per gate).
// Per wave: 128 rows x 16 cols x 4 gates -> acc[8][4] f32x4; epilogue lane-local.
// (a) B fragments load global->VGPR directly (vmcnt path, L2-resident panels,
//     LDS reads 12->8 per wave-slice, LDS A-only 64 KiB);
// (b) A-fragment ds_reads pipelined ONE SLICE AHEAD (drain under MFMA window).
// Slice t: {ldB(t+1)->breg; STAGE_A(t+2); vmcnt(6); BAR; lgkm(0)+schedbar;
//           ds_read A(t+1)->areg; 32 MFMA on A(t)xB(t)}
// vmcnt(6) set-invariant: outstanding after wait = {B(t+1)x4, GLLA(t+2)x2}.

#define GLL(gp, lp) __builtin_amdgcn_global_load_lds( \
        (__attribute__((address_space(1))) void*)(gp), \
        (__attribute__((address_space(3))) void*)(lp), 16, 0, 0)

#define BAR() do { asm volatile("" ::: "memory"); __builtin_amdgcn_s_barrier(); \
                   asm volatile("" ::: "memory"); } while (0)

__global__ __launch_bounds__(512, 2) void lstm_gemm_kernel(
        const unsigned short* __restrict__ Apk,   // [16384][2048]
        const unsigned short* __restrict__ Bpk,   // [4][1024][2048] j-major
        const float* __restrict__ prev_c,
        const float* __restrict__ bi, const float* __restrict__ bf_,
        const float* __restrict__ bo, const float* __restrict__ bu,
        float* __restrict__ out_h, float* __restrict__ out_c) {
    __shared__ __align__(16) unsigned char smem[65536];   // 4 x 16 KiB A buffers
    const int tid = threadIdx.x;
    const int w = tid >> 6, l = tid & 63;
    const int lr = l & 15, s4 = l >> 4;
    const int wm = w >> 2, wq = w & 3;

    // XCD-aware bijective swizzle (nwg=1024 % 8 == 0)
    const int bid = blockIdx.x;
    const int sw = ((bid & 7) << 7) + (bid >> 3);
    const int tileRow = sw & 63, tileCol = sw >> 6;
    const int rowBase = tileRow * 256;
    const int jBase = tileCol * 64;

    // A-fragment read offsets (swizzled involution vs staging slot)
    const int swr = ((s4 ^ ((lr >> 1) & 3)) << 4);
    const int aofBase = (wm * 128 + lr) * 64 + swr;   // + m*1024 per row-tile

    // B direct-load per-lane pointers (gate g): B^T[col][k], 16B contiguous in k
    const int colIdx = jBase + wq * 16 + lr;
    const unsigned short* bPtr0 = Bpk + (((size_t)(0 * 1024 + colIdx)) << 11) + s4 * 8;
    const unsigned short* bPtr1 = Bpk + (((size_t)(1 * 1024 + colIdx)) << 11) + s4 * 8;
    const unsigned short* bPtr2 = Bpk + (((size_t)(2 * 1024 + colIdx)) << 11) + s4 * 8;
    const unsigned short* bPtr3 = Bpk + (((size_t)(3 * 1024 + colIdx)) << 11) + s4 * 8;

    // A staging: per-lane pre-swizzled global source; wave-uniform LDS bases
    const int slot = (l & 3) ^ ((l >> 3) & 3);
    const int rloc = w * 16 + (l >> 2);           // 0..127
    const unsigned short* aSrc0 = Apk + (size_t)(rowBase + rloc) * 2048 + slot * 8;
    const unsigned short* aSrc1 = Apk + (size_t)(rowBase + 128 + rloc) * 2048 + slot * 8;
    const int aDst0 = w * 1024;
    const int aDst1 = 8192 + w * 1024;

#define STAGE_A(T) do { const int _bb = ((T) & 3) * 16384; \
        GLL(aSrc0 + (size_t)(T) * 32, smem + _bb + aDst0); \
        GLL(aSrc1 + (size_t)(T) * 32, smem + _bb + aDst1); } while (0)

    f32x4 acc[8][4];
    const f32x4 vzero = {0.f, 0.f, 0.f, 0.f};
#pragma unroll
    for (int m = 0; m < 8; ++m)
#pragma unroll
        for (int g = 0; g < 4; ++g) acc[m][g] = vzero;

    bf16x8 aE[8], aO[8], bE[4], bO[4];   // parity double-buffered fragments

    auto ldA = [&](int t, bf16x8 (&dst)[8]) {
        const unsigned char* p = smem + (t & 3) * 16384 + aofBase;
#pragma unroll
        for (int m = 0; m < 8; ++m) dst[m] = *(const bf16x8*)(p + m * 1024);
    };
    auto ldB = [&](int t, bf16x8 (&dst)[4]) {
        const size_t o = (size_t)t * 32;
        dst[0] = *(const bf16x8*)(bPtr0 + o);
        dst[1] = *(const bf16x8*)(bPtr1 + o);
        dst[2] = *(const bf16x8*)(bPtr2 + o);
        dst[3] = *(const bf16x8*)(bPtr3 + o);
    };

    // prologue: stage A(0),A(1); load B(0); full drain
    STAGE_A(0); STAGE_A(1);
    ldB(0, bE);
    asm volatile("s_waitcnt vmcnt(0)" ::: "memory");
    BAR();
    ldA(0, aE);   // drained by first slice's lgkm(0)

    auto slice = [&](int t, auto vnc, auto stgc, auto nxtc,
                     bf16x8 (&ac)[8], bf16x8 (&an)[8],
                     bf16x8 (&bc)[4], bf16x8 (&bn)[4]) {
        constexpr int VN = decltype(vnc)::value;
        constexpr bool STG = decltype(stgc)::value;
        constexpr bool NXT = decltype(nxtc)::value;
        if constexpr (NXT) ldB(t + 1, bn);                 // vmem -> regs
        if constexpr (STG) STAGE_A(t + 2);                 // vmem -> LDS
        if constexpr (VN == 6)      asm volatile("s_waitcnt vmcnt(6)" ::: "memory");
        else if constexpr (VN == 4) asm volatile("s_waitcnt vmcnt(4)" ::: "memory");
        else                        asm volatile("s_waitcnt vmcnt(0)" ::: "memory");
        BAR();                                             // publish A(t+1) LDS
        asm volatile("s_waitcnt lgkmcnt(0)" ::: "memory"); // A(t) frag regs ready
        __builtin_amdgcn_sched_barrier(0);                 // rule #18
        if constexpr (NXT) ldA(t + 1, an);                 // drains under MFMA window
        __builtin_amdgcn_s_setprio(1);
#pragma unroll
        for (int m = 0; m < 8; ++m)
#pragma unroll
            for (int g = 0; g < 4; ++g)
                acc[m][g] = __builtin_amdgcn_mfma_f32_16x16x32_bf16(ac[m], bc[g], acc[m][g], 0, 0, 0);
        __builtin_amdgcn_s_setprio(0);
        if constexpr (NXT) {
            __builtin_amdgcn_sched_group_barrier(0x100, 8, 0);  // DS_READ first
            __builtin_amdgcn_sched_group_barrier(0x8,  32, 0);  // then MFMA
        }
    };

    using c6 = std::integral_constant<int, 6>;
    using c4 = std::integral_constant<int, 4>;
    using c0 = std::integral_constant<int, 0>;
    using bT = std::integral_constant<bool, true>;
    using bF = std::integral_constant<bool, false>;

#pragma unroll 1
    for (int t = 0; t < 62; t += 2) {
        slice(t,     c6{}, bT{}, bT{}, aE, aO, bE, bO);    // stages t+2, reads t+1
        slice(t + 1, c6{}, bT{}, bT{}, aO, aE, bO, bE);    // slice 61 stages A(63)
    }
    slice(62, c4{}, bF{}, bT{}, aE, aO, bE, bO);
    slice(63, c0{}, bF{}, bF{}, aO, aE, bO, bE);

    // ---- epilogue: fully lane-local (all 4 gates in-register) ----
    const float vbi = bi[colIdx], vbf = bf_[colIdx], vbo = bo[colIdx], vbu = bu[colIdx];
    const int rowB = rowBase + wm * 128 + s4 * 4;
#pragma unroll
    for (int m = 0; m < 8; ++m) {
#pragma unroll
        for (int tt = 0; tt < 4; ++tt) {
            const size_t idx = (size_t)(rowB + m * 16 + tt) * 1024 + colIdx;
            float zi = acc[m][0][tt] + vbi;
            float zf = acc[m][1][tt] + vbf;
            float zo = acc[m][2][tt] + vbo;
            float zu = acc[m][3][tt] + vbu;
            float iv = fsig(zi), fv = fsig(zf), ov = fsig(zo), uv = ftanh(zu);
            float cv = fv * prev_c[idx] + iv * uv;
            out_c[idx] = cv;
            out_h[idx] = ov * ftanh(cv);
        }
    }
#undef STAGE_A
}

extern "C" void kernel_launch(void* const* d_in, const int* in_sizes, int n_in,
                              void* d_out, int out_size, void* d_ws, size_t ws_size,
                              hipStream_t stream) {
    const float* input  = (const float*)d_in[0];
    const float* prev_h = (const float*)d_in[1];
    const float* prev_c = (const float*)d_in[2];
    const float* wxi = (const float*)d_in[3];
    const float* whi = (const float*)d_in[4];
    const float* wxf = (const float*)d_in[5];
    const float* whf = (const float*)d_in[6];
    const float* wxu = (const float*)d_in[7];
    const float* whu = (const float*)d_in[8];
    const float* wxo = (const float*)d_in[9];
    const float* who = (const float*)d_in[10];
    const float* bi  = (const float*)d_in[11];
    const float* bf_ = (const float*)d_in[12];
    const float* bo  = (const float*)d_in[13];
    const float* bu  = (const float*)d_in[14];

    unsigned short* Apk = (unsigned short*)d_ws;                                  // 64 MiB
    unsigned short* Bpk = (unsigned short*)((char*)d_ws + (size_t)67108864);      // 16 MiB

    float* out_h = (float*)d_out;
    float* out_c = out_h + (size_t)16384 * 1024;

    pack_a_kernel<<<dim3(16384), dim3(256), 0, stream>>>(input, prev_h, Apk);
    pack_b_kernel<<<dim3(4096), dim3(256), 0, stream>>>(wxi, wxf, wxo, wxu,
                                                        whi, whf, who, whu, Bpk);
    lstm_gemm_kernel<<<dim3(1024), dim3(512), 0, stream>>>(Apk, Bpk, prev_c,
                                                           bi, bf_, bo, bu, out_h, out_c);
}

// Round 9
// 336.240 us; speedup vs baseline: 1.2321x; 1.2321x over previous
//
#include <hip/hip_runtime.h>
#include <hip/hip_bf16.h>
#include <stdint.h>
#include <type_traits>

// B=16384, IN=1024, H=1024, K = IN+H = 2048
// Gate order: 0=i, 1=f, 2=o, 3=u
// ws: A_bf16 [16384][2048] @ 0 (64 MiB); B_bf16 [4][1024][2048] (j-major = W^T) @ 64 MiB

typedef short bf16x8 __attribute__((ext_vector_type(8)));
typedef unsigned short u16x8 __attribute__((ext_vector_type(8)));
typedef float f32x4 __attribute__((ext_vector_type(4)));

__device__ __forceinline__ unsigned short f2bf(float f) {
    union { float f; uint32_t u; } v; v.f = f;
    uint32_t r = v.u + 0x7FFFu + ((v.u >> 16) & 1u);   // RNE
    return (unsigned short)(r >> 16);
}

__device__ __forceinline__ float fsig(float x) { return 1.0f / (1.0f + __expf(-x)); }
__device__ __forceinline__ float ftanh(float x) { return 2.0f * fsig(2.0f * x) - 1.0f; }

// ---------------- pack A: [input | prev_h] -> bf16 [16384][2048] ----------------
__global__ __launch_bounds__(256) void pack_a_kernel(const float* __restrict__ input,
                                                     const float* __restrict__ prev_h,
                                                     unsigned short* __restrict__ Apk) {
    long idx = (long)blockIdx.x * 256 + threadIdx.x;
    long e0 = idx * 8;
    int b = (int)(e0 >> 11);
    int k = (int)(e0 & 2047);
    const float* src = (k < 1024) ? (input + (size_t)b * 1024 + k)
                                  : (prev_h + (size_t)b * 1024 + (k - 1024));
    float4 lo = *(const float4*)src;
    float4 hi = *(const float4*)(src + 4);
    u16x8 o;
    o[0] = f2bf(lo.x); o[1] = f2bf(lo.y); o[2] = f2bf(lo.z); o[3] = f2bf(lo.w);
    o[4] = f2bf(hi.x); o[5] = f2bf(hi.y); o[6] = f2bf(hi.z); o[7] = f2bf(hi.w);
    *(u16x8*)(Apk + e0) = o;
}

// ---------------- pack B: per-gate W^T (j-major) bf16 [4][1024][2048] ----------------
__global__ __launch_bounds__(256) void pack_b_kernel(
        const float* __restrict__ wxi, const float* __restrict__ wxf,
        const float* __restrict__ wxo, const float* __restrict__ wxu,
        const float* __restrict__ whi, const float* __restrict__ whf,
        const float* __restrict__ who, const float* __restrict__ whu,
        unsigned short* __restrict__ Bpk) {
    int idx = blockIdx.x * 256 + threadIdx.x;
    int g  = idx >> 18;
    int r  = idx & 262143;
    int kc = r >> 10;
    int j  = r & 1023;
    const float* wx = (g == 0) ? wxi : (g == 1) ? wxf : (g == 2) ? wxo : wxu;
    const float* wh = (g == 0) ? whi : (g == 1) ? whf : (g == 2) ? who : whu;
    int k0 = kc * 8;
    const float* src = (k0 < 1024) ? (wx + (size_t)k0 * 1024 + j)
                                   : (wh + (size_t)(k0 - 1024) * 1024 + j);
    u16x8 o;
#pragma unroll
    for (int t = 0; t < 8; ++t) o[t] = f2bf(src[(size_t)t * 1024]);
    *(u16x8*)(Bpk + (((size_t)(g * 1024 + j)) << 11) + k0) = o;
}

// ---------------- fused GEMM + LSTM epilogue (m201 8-phase port) ----------------
// grid 1024 = 64 rowTiles x 16 colTiles; block 512 = 8 waves; wave (wm,wq).
// Per wave: 128 rows x 16 cols x 4 gates -> acc[8][4]; lane-local epilogue.
// BK=64, 32 K-tiles, 2 x 64 KiB LDS buffers (A[256 rows][128B] + B[256 ec][128B]).
// Per K-tile 4 phases (mh,ks): {ds_read 4-8 b128; 2 GLL piece; [vmcnt@p3]; BAR;
// lgkm(0)+sched_barrier; setprio(1); 16 MFMA; setprio(0); BAR}.
// Piece order: p0->B1(kt+1), p1->A0(kt+1), p2->A1(kt+1) into other buf;
// p3->B0(kt+2) into CURRENT buf (B-half0 fully consumed by p1, 2 barriers prior).
// vmcnt(2) at p3 drains all kt+1 pieces (aged >=1 phase), leaves B0(kt+2).
// XOR swizzle: LDS slot sigma' = slotIdx ^ (row&7) both sides (involution).

#define GLL(gp, lp) __builtin_amdgcn_global_load_lds( \
        (__attribute__((address_space(1))) void*)(gp), \
        (__attribute__((address_space(3))) void*)(lp), 16, 0, 0)

#define BAR() do { asm volatile("" ::: "memory"); __builtin_amdgcn_s_barrier(); \
                   asm volatile("" ::: "memory"); } while (0)

__global__ __launch_bounds__(512, 2) void lstm_gemm_kernel(
        const unsigned short* __restrict__ Apk,   // [16384][2048]
        const unsigned short* __restrict__ Bpk,   // [4][1024][2048] j-major
        const float* __restrict__ prev_c,
        const float* __restrict__ bi, const float* __restrict__ bf_,
        const float* __restrict__ bo, const float* __restrict__ bu,
        float* __restrict__ out_h, float* __restrict__ out_c) {
    __shared__ __align__(16) unsigned char smem[131072];
    const int tid = threadIdx.x;
    const int w = tid >> 6, l = tid & 63;
    const int lr = l & 15, s4 = l >> 4;
    const int wm = w >> 2, wq = w & 3;

    // XCD-aware bijective swizzle (nwg=1024 % 8 == 0)
    const int bid = blockIdx.x;
    const int sw = ((bid & 7) << 7) + (bid >> 3);
    const int tileRow = sw & 63, tileCol = sw >> 6;
    const int rowBase = tileRow * 256;
    const int jBase = tileCol * 64;

    // read-side: slot byte for ks, XORed with row&7 (= lr&7 for all frags)
    const int h7 = lr & 7;
    const int sig0 = ((s4) ^ h7) * 16;          // ks=0
    const int sig1 = ((4 + s4) ^ h7) * 16;      // ks=1
    const int aRdBase = (wm * 128 + lr) * 128;          // A region @ buf+0
    const int bRdBase = 32768 + (wq * 16 + lr) * 128;   // B region @ buf+32768

    // staging: thread writes piece bytes [tid*16]; source pre-swizzled
    const int rloc = tid >> 3;                  // 0..63 (row within 64-row round)
    const int sigS = ((tid & 7) ^ (rloc & 7)) * 8;   // element offset in row
    // A half h, round j: global row = rowBase + h*128 + j*64 + rloc
    const unsigned short* aS00 = Apk + (size_t)(rowBase +   0 +  0 + rloc) * 2048 + sigS;
    const unsigned short* aS01 = Apk + (size_t)(rowBase +   0 + 64 + rloc) * 2048 + sigS;
    const unsigned short* aS10 = Apk + (size_t)(rowBase + 128 +  0 + rloc) * 2048 + sigS;
    const unsigned short* aS11 = Apk + (size_t)(rowBase + 128 + 64 + rloc) * 2048 + sigS;
    // B half h, round j: ec = h*128 + j*64 + rloc; g = ec>>6, c = ec&63
    auto bsrc = [&](int h, int j) {
        int ec = h * 128 + j * 64 + rloc;
        return Bpk + (((size_t)((ec >> 6) * 1024 + jBase + (ec & 63))) << 11) + sigS;
    };
    const unsigned short* bS00 = bsrc(0, 0);
    const unsigned short* bS01 = bsrc(0, 1);
    const unsigned short* bS10 = bsrc(1, 0);
    const unsigned short* bS11 = bsrc(1, 1);

#define STAGE_P(BUFB, P0, P1, DOFF, KT) do { \
        GLL((P0) + (size_t)(KT) * 64, smem + (BUFB) + (DOFF) + w * 1024); \
        GLL((P1) + (size_t)(KT) * 64, smem + (BUFB) + (DOFF) + 8192 + w * 1024); } while (0)

    f32x4 acc[8][4];
    const f32x4 vzero = {0.f, 0.f, 0.f, 0.f};
#pragma unroll
    for (int m = 0; m < 8; ++m)
#pragma unroll
        for (int g = 0; g < 4; ++g) acc[m][g] = vzero;

    bf16x8 aFe[4], aFo[4], bF0[4], bF1[4];

    auto ldA4 = [&](int bufb, int off, bf16x8 (&dst)[4]) {
#pragma unroll
        for (int m = 0; m < 4; ++m)
            dst[m] = *(const bf16x8*)(smem + bufb + aRdBase + off + m * 2048);
    };
    auto ldB4 = [&](int bufb, int sg, bf16x8 (&dst)[4]) {
#pragma unroll
        for (int g = 0; g < 4; ++g)
            dst[g] = *(const bf16x8*)(smem + bufb + bRdBase + sg + g * 8192);
    };

#define LGKM0() do { asm volatile("s_waitcnt lgkmcnt(0)" ::: "memory"); \
                     __builtin_amdgcn_sched_barrier(0); } while (0)
#define MF16(BASE, AR, BR) do { __builtin_amdgcn_s_setprio(1); \
        _Pragma("unroll") \
        for (int m = 0; m < 4; ++m) \
            _Pragma("unroll") \
            for (int g = 0; g < 4; ++g) \
                acc[(BASE) + m][g] = __builtin_amdgcn_mfma_f32_16x16x32_bf16((AR)[m], (BR)[g], acc[(BASE) + m][g], 0, 0, 0); \
        __builtin_amdgcn_s_setprio(0); } while (0)

    // prologue: stage K-tile 0 fully (buf0) + B0 of K-tile 1 (buf1); drain to 2
    STAGE_P(0, bS00, bS01, 32768, 0);
    STAGE_P(0, bS10, bS11, 32768 + 16384, 0);
    STAGE_P(0, aS00, aS01, 0, 0);
    STAGE_P(0, aS10, aS11, 16384, 0);
    STAGE_P(65536, bS00, bS01, 32768, 1);
    asm volatile("s_waitcnt vmcnt(2)" ::: "memory");
    BAR();

    auto ktile = [&](int kt, auto modeC) {
        constexpr int MODE = decltype(modeC)::value;  // 0 steady, 1 kt=30, 2 kt=31
        const int bufb = (kt & 1) * 65536;
        const int othb = bufb ^ 65536;
        // ---- p0: (mh0, ks0) ----
        ldB4(bufb, sig0, bF0);
        ldA4(bufb, sig0, aFe);
        if constexpr (MODE <= 1) STAGE_P(othb, bS10, bS11, 32768 + 16384, kt + 1);
        BAR(); LGKM0();
        MF16(0, aFe, bF0);
        BAR();
        // ---- p1: (mh0, ks1) ----
        ldB4(bufb, sig1, bF1);
        ldA4(bufb, sig1, aFo);
        if constexpr (MODE <= 1) STAGE_P(othb, aS00, aS01, 0, kt + 1);
        BAR(); LGKM0();
        MF16(0, aFo, bF1);
        BAR();
        // ---- p2: (mh1, ks0) ----
        ldA4(bufb, 8192 + sig0, aFe);
        if constexpr (MODE <= 1) STAGE_P(othb, aS10, aS11, 16384, kt + 1);
        BAR(); LGKM0();
        MF16(4, aFe, bF0);
        BAR();
        // ---- p3: (mh1, ks1) ----
        ldA4(bufb, 8192 + sig1, aFo);
        if constexpr (MODE == 0) STAGE_P(bufb, bS00, bS01, 32768, kt + 2);
        if constexpr (MODE == 0)      asm volatile("s_waitcnt vmcnt(2)" ::: "memory");
        else if constexpr (MODE == 1) asm volatile("s_waitcnt vmcnt(0)" ::: "memory");
        BAR(); LGKM0();
        MF16(4, aFo, bF1);
        BAR();
    };

    using m0 = std::integral_constant<int, 0>;
    using m1 = std::integral_constant<int, 1>;
    using m2 = std::integral_constant<int, 2>;

#pragma unroll 1
    for (int kt = 0; kt < 30; ++kt) ktile(kt, m0{});
    ktile(30, m1{});
    ktile(31, m2{});

    // ---- epilogue: fully lane-local; acc[m] rows = (m>>2)*64 + (m&3)*16 ----
    const int colIdx = jBase + wq * 16 + lr;
    const float vbi = bi[colIdx], vbf = bf_[colIdx], vbo = bo[colIdx], vbu = bu[colIdx];
    const int rowB = rowBase + wm * 128 + s4 * 4;
#pragma unroll
    for (int m = 0; m < 8; ++m) {
        const int rOff = (m >> 2) * 64 + (m & 3) * 16;
#pragma unroll
        for (int tt = 0; tt < 4; ++tt) {
            const size_t idx = (size_t)(rowB + rOff + tt) * 1024 + colIdx;
            float zi = acc[m][0][tt] + vbi;
            float zf = acc[m][1][tt] + vbf;
            float zo = acc[m][2][tt] + vbo;
            float zu = acc[m][3][tt] + vbu;
            float iv = fsig(zi), fv = fsig(zf), ov = fsig(zo), uv = ftanh(zu);
            float cv = fv * prev_c[idx] + iv * uv;
            out_c[idx] = cv;
            out_h[idx] = ov * ftanh(cv);
        }
    }
#undef STAGE_P
#undef LGKM0
#undef MF16
}

extern "C" void kernel_launch(void* const* d_in, const int* in_sizes, int n_in,
                              void* d_out, int out_size, void* d_ws, size_t ws_size,
                              hipStream_t stream) {
    const float* input  = (const float*)d_in[0];
    const float* prev_h = (const float*)d_in[1];
    const float* prev_c = (const float*)d_in[2];
    const float* wxi = (const float*)d_in[3];
    const float* whi = (const float*)d_in[4];
    const float* wxf = (const float*)d_in[5];
    const float* whf = (const float*)d_in[6];
    const float* wxu = (const float*)d_in[7];
    const float* whu = (const float*)d_in[8];
    const float* wxo = (const float*)d_in[9];
    const float* who = (const float*)d_in[10];
    const float* bi  = (const float*)d_in[11];
    const float* bf_ = (const float*)d_in[12];
    const float* bo  = (const float*)d_in[13];
    const float* bu  = (const float*)d_in[14];

    unsigned short* Apk = (unsigned short*)d_ws;                                  // 64 MiB
    unsigned short* Bpk = (unsigned short*)((char*)d_ws + (size_t)67108864);      // 16 MiB

    float* out_h = (float*)d_out;
    float* out_c = out_h + (size_t)16384 * 1024;

    pack_a_kernel<<<dim3(16384), dim3(256), 0, stream>>>(input, prev_h, Apk);
    pack_b_kernel<<<dim3(4096), dim3(256), 0, stream>>>(wxi, wxf, wxo, wxu,
                                                        whi, whf, who, whu, Bpk);
    lstm_gemm_kernel<<<dim3(1024), dim3(512), 0, stream>>>(Apk, Bpk, prev_c,
                                                           bi, bf_, bo, bu, out_h, out_c);
}

// Round 10
// 332.909 us; speedup vs baseline: 1.2444x; 1.0100x over previous
//
#include <hip/hip_runtime.h>
#include <hip/hip_bf16.h>
#include <stdint.h>
#include <type_traits>

// B=16384, IN=1024, H=1024, K = IN+H = 2048
// Gate order: 0=i, 1=f, 2=o, 3=u
// ws: A_bf16 [16384][2048] @ 0 (64 MiB); B_bf16 [4][1024][2048] (j-major = W^T) @ 64 MiB

typedef short bf16x8 __attribute__((ext_vector_type(8)));
typedef unsigned short u16x8 __attribute__((ext_vector_type(8)));
typedef float f32x4 __attribute__((ext_vector_type(4)));

__device__ __forceinline__ unsigned short f2bf(float f) {
    union { float f; uint32_t u; } v; v.f = f;
    uint32_t r = v.u + 0x7FFFu + ((v.u >> 16) & 1u);   // RNE
    return (unsigned short)(r >> 16);
}

__device__ __forceinline__ float fsig(float x) { return 1.0f / (1.0f + __expf(-x)); }
__device__ __forceinline__ float ftanh(float x) { return 2.0f * fsig(2.0f * x) - 1.0f; }

// ---------------- pack A: [input | prev_h] -> bf16 [16384][2048] ----------------
__global__ __launch_bounds__(256) void pack_a_kernel(const float* __restrict__ input,
                                                     const float* __restrict__ prev_h,
                                                     unsigned short* __restrict__ Apk) {
    long idx = (long)blockIdx.x * 256 + threadIdx.x;
    long e0 = idx * 8;
    int b = (int)(e0 >> 11);
    int k = (int)(e0 & 2047);
    const float* src = (k < 1024) ? (input + (size_t)b * 1024 + k)
                                  : (prev_h + (size_t)b * 1024 + (k - 1024));
    float4 lo = *(const float4*)src;
    float4 hi = *(const float4*)(src + 4);
    u16x8 o;
    o[0] = f2bf(lo.x); o[1] = f2bf(lo.y); o[2] = f2bf(lo.z); o[3] = f2bf(lo.w);
    o[4] = f2bf(hi.x); o[5] = f2bf(hi.y); o[6] = f2bf(hi.z); o[7] = f2bf(hi.w);
    *(u16x8*)(Apk + e0) = o;
}

// ---------------- pack B: per-gate W^T (j-major) bf16 [4][1024][2048] ----------------
__global__ __launch_bounds__(256) void pack_b_kernel(
        const float* __restrict__ wxi, const float* __restrict__ wxf,
        const float* __restrict__ wxo, const float* __restrict__ wxu,
        const float* __restrict__ whi, const float* __restrict__ whf,
        const float* __restrict__ who, const float* __restrict__ whu,
        unsigned short* __restrict__ Bpk) {
    int idx = blockIdx.x * 256 + threadIdx.x;
    int g  = idx >> 18;
    int r  = idx & 262143;
    int kc = r >> 10;
    int j  = r & 1023;
    const float* wx = (g == 0) ? wxi : (g == 1) ? wxf : (g == 2) ? wxo : wxu;
    const float* wh = (g == 0) ? whi : (g == 1) ? whf : (g == 2) ? who : whu;
    int k0 = kc * 8;
    const float* src = (k0 < 1024) ? (wx + (size_t)k0 * 1024 + j)
                                   : (wh + (size_t)(k0 - 1024) * 1024 + j);
    u16x8 o;
#pragma unroll
    for (int t = 0; t < 8; ++t) o[t] = f2bf(src[(size_t)t * 1024]);
    *(u16x8*)(Bpk + (((size_t)(g * 1024 + j)) << 11) + k0) = o;
}

// ---------------- fused GEMM + LSTM epilogue (8-phase, compiler-scheduled waits) ----------------
// Identical to R9 EXCEPT: the forced per-phase {lgkmcnt(0) + sched_barrier(0)} is
// REMOVED. ds_reads are C++ loads -> compiler inserts minimal per-dependency
// lgkmcnt(N) waits, so early MFMAs issue while later reads drain (read-drain ||
// MFMA overlap within each phase). Safety: every read is drained before its
// consuming MFMA issues (dep wait) -> before that wave's trailing barrier ->
// transitively >=2 barriers before any GLL overwrites those LDS bytes.
// vmcnt stays PRE-barrier (cross-wave GLL publish).

#define GLL(gp, lp) __builtin_amdgcn_global_load_lds( \
        (__attribute__((address_space(1))) void*)(gp), \
        (__attribute__((address_space(3))) void*)(lp), 16, 0, 0)

#define BAR() do { asm volatile("" ::: "memory"); __builtin_amdgcn_s_barrier(); \
                   asm volatile("" ::: "memory"); } while (0)

__global__ __launch_bounds__(512, 2) void lstm_gemm_kernel(
        const unsigned short* __restrict__ Apk,   // [16384][2048]
        const unsigned short* __restrict__ Bpk,   // [4][1024][2048] j-major
        const float* __restrict__ prev_c,
        const float* __restrict__ bi, const float* __restrict__ bf_,
        const float* __restrict__ bo, const float* __restrict__ bu,
        float* __restrict__ out_h, float* __restrict__ out_c) {
    __shared__ __align__(16) unsigned char smem[131072];
    const int tid = threadIdx.x;
    const int w = tid >> 6, l = tid & 63;
    const int lr = l & 15, s4 = l >> 4;
    const int wm = w >> 2, wq = w & 3;

    // XCD-aware bijective swizzle (nwg=1024 % 8 == 0)
    const int bid = blockIdx.x;
    const int sw = ((bid & 7) << 7) + (bid >> 3);
    const int tileRow = sw & 63, tileCol = sw >> 6;
    const int rowBase = tileRow * 256;
    const int jBase = tileCol * 64;

    // read-side: slot byte for ks, XORed with row&7 (= lr&7 for all frags)
    const int h7 = lr & 7;
    const int sig0 = ((s4) ^ h7) * 16;          // ks=0
    const int sig1 = ((4 + s4) ^ h7) * 16;      // ks=1
    const int aRdBase = (wm * 128 + lr) * 128;          // A region @ buf+0
    const int bRdBase = 32768 + (wq * 16 + lr) * 128;   // B region @ buf+32768

    // staging: thread writes piece bytes [tid*16]; source pre-swizzled
    const int rloc = tid >> 3;                  // 0..63 (row within 64-row round)
    const int sigS = ((tid & 7) ^ (rloc & 7)) * 8;   // element offset in row
    const unsigned short* aS00 = Apk + (size_t)(rowBase +   0 +  0 + rloc) * 2048 + sigS;
    const unsigned short* aS01 = Apk + (size_t)(rowBase +   0 + 64 + rloc) * 2048 + sigS;
    const unsigned short* aS10 = Apk + (size_t)(rowBase + 128 +  0 + rloc) * 2048 + sigS;
    const unsigned short* aS11 = Apk + (size_t)(rowBase + 128 + 64 + rloc) * 2048 + sigS;
    auto bsrc = [&](int h, int j) {
        int ec = h * 128 + j * 64 + rloc;
        return Bpk + (((size_t)((ec >> 6) * 1024 + jBase + (ec & 63))) << 11) + sigS;
    };
    const unsigned short* bS00 = bsrc(0, 0);
    const unsigned short* bS01 = bsrc(0, 1);
    const unsigned short* bS10 = bsrc(1, 0);
    const unsigned short* bS11 = bsrc(1, 1);

#define STAGE_P(BUFB, P0, P1, DOFF, KT) do { \
        GLL((P0) + (size_t)(KT) * 64, smem + (BUFB) + (DOFF) + w * 1024); \
        GLL((P1) + (size_t)(KT) * 64, smem + (BUFB) + (DOFF) + 8192 + w * 1024); } while (0)

    f32x4 acc[8][4];
    const f32x4 vzero = {0.f, 0.f, 0.f, 0.f};
#pragma unroll
    for (int m = 0; m < 8; ++m)
#pragma unroll
        for (int g = 0; g < 4; ++g) acc[m][g] = vzero;

    bf16x8 aFe[4], aFo[4], bF0[4], bF1[4];

    auto ldA4 = [&](int bufb, int off, bf16x8 (&dst)[4]) {
#pragma unroll
        for (int m = 0; m < 4; ++m)
            dst[m] = *(const bf16x8*)(smem + bufb + aRdBase + off + m * 2048);
    };
    auto ldB4 = [&](int bufb, int sg, bf16x8 (&dst)[4]) {
#pragma unroll
        for (int g = 0; g < 4; ++g)
            dst[g] = *(const bf16x8*)(smem + bufb + bRdBase + sg + g * 8192);
    };

#define MF16(BASE, AR, BR) do { __builtin_amdgcn_s_setprio(1); \
        _Pragma("unroll") \
        for (int m = 0; m < 4; ++m) \
            _Pragma("unroll") \
            for (int g = 0; g < 4; ++g) \
                acc[(BASE) + m][g] = __builtin_amdgcn_mfma_f32_16x16x32_bf16((AR)[m], (BR)[g], acc[(BASE) + m][g], 0, 0, 0); \
        __builtin_amdgcn_s_setprio(0); } while (0)

    // prologue: stage K-tile 0 fully (buf0) + B0 of K-tile 1 (buf1); drain to 2
    STAGE_P(0, bS00, bS01, 32768, 0);
    STAGE_P(0, bS10, bS11, 32768 + 16384, 0);
    STAGE_P(0, aS00, aS01, 0, 0);
    STAGE_P(0, aS10, aS11, 16384, 0);
    STAGE_P(65536, bS00, bS01, 32768, 1);
    asm volatile("s_waitcnt vmcnt(2)" ::: "memory");
    BAR();

    auto ktile = [&](int kt, auto modeC) {
        constexpr int MODE = decltype(modeC)::value;  // 0 steady, 1 kt=30, 2 kt=31
        const int bufb = (kt & 1) * 65536;
        const int othb = bufb ^ 65536;
        // ---- p0: (mh0, ks0) ----
        ldB4(bufb, sig0, bF0);
        ldA4(bufb, sig0, aFe);
        if constexpr (MODE <= 1) STAGE_P(othb, bS10, bS11, 32768 + 16384, kt + 1);
        BAR();
        MF16(0, aFe, bF0);
        BAR();
        // ---- p1: (mh0, ks1) ----
        ldB4(bufb, sig1, bF1);
        ldA4(bufb, sig1, aFo);
        if constexpr (MODE <= 1) STAGE_P(othb, aS00, aS01, 0, kt + 1);
        BAR();
        MF16(0, aFo, bF1);
        BAR();
        // ---- p2: (mh1, ks0) ----
        ldA4(bufb, 8192 + sig0, aFe);
        if constexpr (MODE <= 1) STAGE_P(othb, aS10, aS11, 16384, kt + 1);
        BAR();
        MF16(4, aFe, bF0);
        BAR();
        // ---- p3: (mh1, ks1) ----
        ldA4(bufb, 8192 + sig1, aFo);
        if constexpr (MODE == 0) STAGE_P(bufb, bS00, bS01, 32768, kt + 2);
        if constexpr (MODE == 0)      asm volatile("s_waitcnt vmcnt(2)" ::: "memory");
        else if constexpr (MODE == 1) asm volatile("s_waitcnt vmcnt(0)" ::: "memory");
        BAR();
        MF16(4, aFo, bF1);
        BAR();
    };

    using m0 = std::integral_constant<int, 0>;
    using m1 = std::integral_constant<int, 1>;
    using m2 = std::integral_constant<int, 2>;

#pragma unroll 1
    for (int kt = 0; kt < 30; ++kt) ktile(kt, m0{});
    ktile(30, m1{});
    ktile(31, m2{});

    // ---- epilogue: fully lane-local; acc[m] rows = (m>>2)*64 + (m&3)*16 ----
    const int colIdx = jBase + wq * 16 + lr;
    const float vbi = bi[colIdx], vbf = bf_[colIdx], vbo = bo[colIdx], vbu = bu[colIdx];
    const int rowB = rowBase + wm * 128 + s4 * 4;
#pragma unroll
    for (int m = 0; m < 8; ++m) {
        const int rOff = (m >> 2) * 64 + (m & 3) * 16;
#pragma unroll
        for (int tt = 0; tt < 4; ++tt) {
            const size_t idx = (size_t)(rowB + rOff + tt) * 1024 + colIdx;
            float zi = acc[m][0][tt] + vbi;
            float zf = acc[m][1][tt] + vbf;
            float zo = acc[m][2][tt] + vbo;
            float zu = acc[m][3][tt] + vbu;
            float iv = fsig(zi), fv = fsig(zf), ov = fsig(zo), uv = ftanh(zu);
            float cv = fv * prev_c[idx] + iv * uv;
            out_c[idx] = cv;
            out_h[idx] = ov * ftanh(cv);
        }
    }
#undef STAGE_P
#undef MF16
}

extern "C" void kernel_launch(void* const* d_in, const int* in_sizes, int n_in,
                              void* d_out, int out_size, void* d_ws, size_t ws_size,
                              hipStream_t stream) {
    const float* input  = (const float*)d_in[0];
    const float* prev_h = (const float*)d_in[1];
    const float* prev_c = (const float*)d_in[2];
    const float* wxi = (const float*)d_in[3];
    const float* whi = (const float*)d_in[4];
    const float* wxf = (const float*)d_in[5];
    const float* whf = (const float*)d_in[6];
    const float* wxu = (const float*)d_in[7];
    const float* whu = (const float*)d_in[8];
    const float* wxo = (const float*)d_in[9];
    const float* who = (const float*)d_in[10];
    const float* bi  = (const float*)d_in[11];
    const float* bf_ = (const float*)d_in[12];
    const float* bo  = (const float*)d_in[13];
    const float* bu  = (const float*)d_in[14];

    unsigned short* Apk = (unsigned short*)d_ws;                                  // 64 MiB
    unsigned short* Bpk = (unsigned short*)((char*)d_ws + (size_t)67108864);      // 16 MiB

    float* out_h = (float*)d_out;
    float* out_c = out_h + (size_t)16384 * 1024;

    pack_a_kernel<<<dim3(16384), dim3(256), 0, stream>>>(input, prev_h, Apk);
    pack_b_kernel<<<dim3(4096), dim3(256), 0, stream>>>(wxi, wxf, wxo, wxu,
                                                        whi, whf, who, whu, Bpk);
    lstm_gemm_kernel<<<dim3(1024), dim3(512), 0, stream>>>(Apk, Bpk, prev_c,
                                                           bi, bf_, bo, bu, out_h, out_c);
}